// Round 1
// baseline (191.385 us; speedup 1.0000x reference)
//
#include <hip/hip_runtime.h>
#include <math.h>

#define B_ 8
#define N_ 2000
#define H_ 128
#define K_ 32
#define M_ (B_*N_)     // 16000
#define KTOT 384       // [in_agg(128) | out_agg(128) | h(128)]
#define NC 512         // cols j = d*4 + g
#define NTILES 32      // NC/16
#define NCHUNK 12      // KTOT/32
#define AGG_BLOCKS (M_ / 8)           // 2000
#define PREP_BLOCKS (NTILES * NCHUNK) // 384
#define GEMM_BLOCKS 1024              // 8 XCDs x <=128 tile-slots (128x64 tiles)

typedef __attribute__((ext_vector_type(8))) short s8_t;
typedef __attribute__((ext_vector_type(4))) float f4_t;

__device__ __forceinline__ unsigned short f2bf(float x) {
    union { float f; unsigned u; } v; v.f = x;
    unsigned r = v.u + 0x7fff + ((v.u >> 16) & 1);   // RN-even
    return (unsigned short)(r >> 16);
}
__device__ __forceinline__ float bf2f(unsigned short b) {
    union { unsigned u; float f; } v; v.u = (unsigned)b << 16; return v.f;
}
__device__ __forceinline__ float sigm_(float x) { return 1.f / (1.f + __expf(-x)); }
__device__ __forceinline__ float tanh_(float x) { return 2.f / (1.f + __expf(-2.f * x)) - 1.f; }

__device__ __forceinline__ float pickv(f4_t A, int m) {
    float ab = (m & 1) ? A.y : A.x;
    float cd = (m & 1) ? A.w : A.z;
    return (m & 2) ? cd : ab;
}
__device__ __forceinline__ float pick4(float u0, float u1, float u2, float u3, int m) {
    float ab = (m & 1) ? u1 : u0;
    float cd = (m & 1) ? u3 : u2;
    return (m & 2) ? cd : ab;
}

__device__ __forceinline__ void split4(const float* f, ushort4& hi, ushort4& lo) {
    unsigned short h0 = f2bf(f[0]), h1 = f2bf(f[1]), h2 = f2bf(f[2]), h3 = f2bf(f[3]);
    hi = make_ushort4(h0, h1, h2, h3);
    lo = make_ushort4(f2bf(f[0] - bf2f(h0)), f2bf(f[1] - bf2f(h1)),
                      f2bf(f[2] - bf2f(h2)), f2bf(f[3] - bf2f(h3)));
}

// W prep: element t (0..511) of prep-block pb = (ntile*NCHUNK + chunk).
__device__ __forceinline__ void prep_elem(int pb, int t,
                                          const float* __restrict__ w_in,
                                          const float* __restrict__ w_out,
                                          const float* __restrict__ u_in,
                                          const float* __restrict__ u_out,
                                          unsigned short* __restrict__ wp_hi,
                                          unsigned short* __restrict__ wp_lo) {
    int ntile = pb / NCHUNK, chunk = pb % NCHUNK;
    int lane = t >> 3, e = t & 7;
    int col = ntile * 16 + (lane & 15);
    int k = chunk * 32 + (lane >> 4) * 8 + e;
    int d = col >> 2, g = col & 3;
    float v;
    if (k < 128) {
        v = w_in[(g * 128 + k) * 128 + d];
    } else if (k < 256) {
        v = w_out[(g * 128 + (k - 128)) * 128 + d];
    } else {
        int kk = k - 256;
        v = u_in[(g * 128 + kk) * 128 + d] + u_out[(g * 128 + kk) * 128 + d];
    }
    unsigned short hs = f2bf(v);
    wp_hi[(size_t)pb * 512 + t] = hs;
    wp_lo[(size_t)pb * 512 + t] = f2bf(v - bf2f(hs));
}

// Gather + masked aggregate + u-term pack for agg-unit a (rows 8a..8a+7);
// output split-bf16 in MFMA A-fragment layout (verified R4-R11).
__device__ __forceinline__ void agg_body(int a, int tid,
                                         const float* __restrict__ h,
                                         const int* __restrict__ in_idx,
                                         const float* __restrict__ in_mask,
                                         const int* __restrict__ out_idx,
                                         const float* __restrict__ out_mask,
                                         unsigned short* __restrict__ A_hi,
                                         unsigned short* __restrict__ A_lo,
                                         int (*s_idx)[64], float (*s_msk)[64]) {
    int r = tid >> 5;            // 0..7 row within unit
    int p = tid & 31;            // dim group: dims p*4 .. p*4+3
    int row = a * 8 + r;
    int b = row / N_;
    const float* hb = h + (size_t)b * N_ * H_;

    for (int e = tid; e < 512; e += 256) {
        int r2 = e >> 6, q = e & 63;
        int ridx = a * 8 + r2;
        if (q < 32) {
            s_idx[r2][q] = in_idx[ridx * K_ + q];
            s_msk[r2][q] = in_mask[ridx * K_ + q];
        } else {
            s_idx[r2][q] = out_idx[ridx * K_ + (q - 32)];
            s_msk[r2][q] = out_mask[ridx * K_ + (q - 32)];
        }
    }
    __syncthreads();

    int d0 = p * 4;
    float ai[4] = {0.f, 0.f, 0.f, 0.f};
    float ao[4] = {0.f, 0.f, 0.f, 0.f};
    #pragma unroll 16
    for (int k = 0; k < K_; ++k) {
        int   i1 = s_idx[r][k];
        float m1 = s_msk[r][k];
        int   i2 = s_idx[r][32 + k];
        float m2 = s_msk[r][32 + k];
        float4 v1 = *(const float4*)(hb + (size_t)i1 * H_ + d0);
        float4 v2 = *(const float4*)(hb + (size_t)i2 * H_ + d0);
        ai[0] += m1 * v1.x; ai[1] += m1 * v1.y; ai[2] += m1 * v1.z; ai[3] += m1 * v1.w;
        ao[0] += m2 * v2.x; ao[1] += m2 * v2.y; ao[2] += m2 * v2.z; ao[3] += m2 * v2.w;
    }
    float4 hv4 = *(const float4*)(h + (size_t)row * H_ + d0);
    float hh[4] = {hv4.x, hv4.y, hv4.z, hv4.w};

    int mtile = row >> 4;
    int kg = (p >> 1) & 3;
    int e0 = (p & 1) * 4;
    int lane = (row & 15) + 16 * kg;
    size_t bi = ((size_t)(mtile * NCHUNK +     (p >> 3)) * 64 + lane) * 8 + e0;
    size_t bo = ((size_t)(mtile * NCHUNK + 4 + (p >> 3)) * 64 + lane) * 8 + e0;
    size_t bh = ((size_t)(mtile * NCHUNK + 8 + (p >> 3)) * 64 + lane) * 8 + e0;

    ushort4 hi, lo;
    split4(ai, hi, lo); *(ushort4*)(A_hi + bi) = hi; *(ushort4*)(A_lo + bi) = lo;
    split4(ao, hi, lo); *(ushort4*)(A_hi + bo) = hi; *(ushort4*)(A_lo + bo) = lo;
    split4(hh, hi, lo); *(ushort4*)(A_hi + bh) = hi; *(ushort4*)(A_lo + bh) = lo;
}

// Layer-0 combined dispatch: blocks [0,2000) = agg on node_hidden,
// blocks [2000, 2384) = W prep.
__global__ __launch_bounds__(256)
void agg0_prep_kernel(const float* __restrict__ h,
                      const int* __restrict__ in_idx,
                      const float* __restrict__ in_mask,
                      const int* __restrict__ out_idx,
                      const float* __restrict__ out_mask,
                      unsigned short* __restrict__ A_hi,
                      unsigned short* __restrict__ A_lo,
                      const float* __restrict__ w_in,
                      const float* __restrict__ w_out,
                      const float* __restrict__ u_in,
                      const float* __restrict__ u_out,
                      unsigned short* __restrict__ wp_hi,
                      unsigned short* __restrict__ wp_lo) {
    __shared__ int   s_idx[8][64];
    __shared__ float s_msk[8][64];
    int tid = threadIdx.x;
    if (blockIdx.x < AGG_BLOCKS) {
        int bid = (blockIdx.x & 7) * 250 + (blockIdx.x >> 3);  // XCD-affinity swizzle
        agg_body(bid, tid, h, in_idx, in_mask, out_idx, out_mask,
                 A_hi, A_lo, s_idx, s_msk);
    } else {
        int pb = blockIdx.x - AGG_BLOCKS;
        prep_elem(pb, tid,       w_in, w_out, u_in, u_out, wp_hi, wp_lo);
        prep_elem(pb, tid + 256, w_in, w_out, u_in, u_out, wp_hi, wp_lo);
    }
}

// Layer-1 agg (h = h_buf)
__global__ __launch_bounds__(256)
void agg_kernel(const float* __restrict__ h,
                const int* __restrict__ in_idx,
                const float* __restrict__ in_mask,
                const int* __restrict__ out_idx,
                const float* __restrict__ out_mask,
                unsigned short* __restrict__ A_hi,
                unsigned short* __restrict__ A_lo) {
    __shared__ int   s_idx[8][64];
    __shared__ float s_msk[8][64];
    int bid = (blockIdx.x & 7) * 250 + (blockIdx.x >> 3);
    agg_body(bid, threadIdx.x, h, in_idx, in_mask, out_idx, out_mask,
             A_hi, A_lo, s_idx, s_msk);
}

// gemm v5: 128x64 block tile, NO LDS / NO barriers. A and W are stored in
// MFMA A-fragment layout, so each wave loads its fragments straight from
// global into VGPRs (coalesced dwordx4 per lane). Register double-buffer
// (compile-time indices) lets the compiler keep next-chunk loads in flight
// under the current chunk's 24 MFMAs with counted vmcnt -- removes the
// per-chunk vmcnt(0)+s_barrier drain of the LDS-staged version.
__device__ __forceinline__ void load_chunk(
        const unsigned short* const (&pa_hi)[4],
        const unsigned short* const (&pa_lo)[4],
        const unsigned short* const (&pb_hi)[2],
        const unsigned short* const (&pb_lo)[2],
        int c,
        s8_t (&ah)[4], s8_t (&al)[4], s8_t (&bh)[2], s8_t (&bl)[2]) {
    #pragma unroll
    for (int i = 0; i < 4; ++i) {
        ah[i] = *(const s8_t*)(pa_hi[i] + (size_t)c * 512);
        al[i] = *(const s8_t*)(pa_lo[i] + (size_t)c * 512);
    }
    #pragma unroll
    for (int j = 0; j < 2; ++j) {
        bh[j] = *(const s8_t*)(pb_hi[j] + (size_t)c * 512);
        bl[j] = *(const s8_t*)(pb_lo[j] + (size_t)c * 512);
    }
}

__device__ __forceinline__ void mfma_chunk(
        const s8_t (&ah)[4], const s8_t (&al)[4],
        const s8_t (&bh)[2], const s8_t (&bl)[2],
        f4_t (&acc)[4][2]) {
    #pragma unroll
    for (int i = 0; i < 4; ++i)
        #pragma unroll
        for (int j = 0; j < 2; ++j) {
            acc[i][j] = __builtin_amdgcn_mfma_f32_16x16x32_bf16(ah[i], bh[j], acc[i][j], 0, 0, 0);
            acc[i][j] = __builtin_amdgcn_mfma_f32_16x16x32_bf16(ah[i], bl[j], acc[i][j], 0, 0, 0);
            acc[i][j] = __builtin_amdgcn_mfma_f32_16x16x32_bf16(al[i], bh[j], acc[i][j], 0, 0, 0);
        }
}

__global__ __launch_bounds__(256)
void gemm_gates(const unsigned short* __restrict__ A_hi,
                const unsigned short* __restrict__ A_lo,
                const unsigned short* __restrict__ wp_hi,
                const unsigned short* __restrict__ wp_lo,
                const float* __restrict__ bias,
                const float* __restrict__ c_src,
                float* __restrict__ c_dst,
                float* __restrict__ h_dst,
                int write_c) {
    int l = blockIdx.x;
    int x = l & 7;                   // XCD (round-robin dispatch)
    int s_slot = l >> 3;             // 0..127
    int mt_lo  = x ? ((2000 * x + 63) >> 7) : 0;
    int mt_nxt = (2000 * (x + 1) + 63) >> 7;         // x=7 -> 125
    int cnt = (mt_nxt - mt_lo) * 8;                  // <=128
    if (s_slot >= cnt) return;
    int mt = mt_lo + (s_slot >> 3);                  // 0..124 (128-row tile)
    int jt = s_slot & 7;                             // 0..7  (64-col tile)

    int tid  = threadIdx.x;
    int lane = tid & 63;
    int w    = tid >> 6;         // 0..3
    int wm   = w & 1;            // 64-row half
    int wn   = w >> 1;           // 32-col half
    int mtile0 = mt * 8;
    int ntile0 = jt * 4;

    // fragment base pointers: frag(i, chunk c) = base + c*512 shorts
    const unsigned short* pa_hi[4];
    const unsigned short* pa_lo[4];
    const unsigned short* pb_hi[2];
    const unsigned short* pb_lo[2];
    #pragma unroll
    for (int i = 0; i < 4; ++i) {
        size_t off = (size_t)(mtile0 + wm * 4 + i) * (NCHUNK * 512) + lane * 8;
        pa_hi[i] = A_hi + off;
        pa_lo[i] = A_lo + off;
    }
    #pragma unroll
    for (int j = 0; j < 2; ++j) {
        size_t off = (size_t)(ntile0 + wn * 2 + j) * (NCHUNK * 512) + lane * 8;
        pb_hi[j] = wp_hi + off;
        pb_lo[j] = wp_lo + off;
    }

    f4_t zero = {0.f, 0.f, 0.f, 0.f};
    f4_t acc[4][2];
    #pragma unroll
    for (int i = 0; i < 4; ++i)
        #pragma unroll
        for (int j = 0; j < 2; ++j) acc[i][j] = zero;

    // register double-buffer over the 12 K-chunks (all indices static)
    s8_t ah0[4], al0[4], bh0[2], bl0[2];
    s8_t ah1[4], al1[4], bh1[2], bl1[2];
    load_chunk(pa_hi, pa_lo, pb_hi, pb_lo, 0, ah0, al0, bh0, bl0);
    #pragma unroll 1
    for (int c = 0; c < NCHUNK - 2; c += 2) {
        load_chunk(pa_hi, pa_lo, pb_hi, pb_lo, c + 1, ah1, al1, bh1, bl1);
        mfma_chunk(ah0, al0, bh0, bl0, acc);
        load_chunk(pa_hi, pa_lo, pb_hi, pb_lo, c + 2, ah0, al0, bh0, bl0);
        mfma_chunk(ah1, al1, bh1, bl1, acc);
    }
    load_chunk(pa_hi, pa_lo, pb_hi, pb_lo, NCHUNK - 1, ah1, al1, bh1, bl1);
    mfma_chunk(ah0, al0, bh0, bl0, acc);
    mfma_chunk(ah1, al1, bh1, bl1, acc);

    // ---- epilogue: gate exchange + cell/h update (verified R2-R11) ----
    int g    = lane & 3;
    int qrow = lane >> 4;
    int dl   = (lane >> 2) & 3;
    #pragma unroll
    for (int j = 0; j < 2; ++j) {
        int ncol_base = jt * 64 + wn * 32 + j * 16;
        int d = (ncol_base >> 2) + dl;
        float b0 = bias[0 * 128 + d];
        float b1 = bias[1 * 128 + d];
        float b2 = bias[2 * 128 + d];
        float b3 = bias[3 * 128 + d];
        #pragma unroll
        for (int i = 0; i < 4; ++i) {
            f4_t A = acc[i][j];
            float s0 = pickv(A, g);
            float s1 = pickv(A, g ^ 1);
            float s2 = pickv(A, g ^ 2);
            float s3 = pickv(A, g ^ 3);
            float u0 = s0;
            float u1 = __shfl_xor(s1, 1);
            float u2 = __shfl_xor(s2, 2);
            float u3 = __shfl_xor(s3, 3);
            float p0 = pick4(u0, u1, u2, u3, g) + b0;
            float p1 = pick4(u0, u1, u2, u3, g ^ 1) + b1;
            float p2 = pick4(u0, u1, u2, u3, g ^ 2) + b2;
            float p3 = pick4(u0, u1, u2, u3, g ^ 3) + b3;
            float ig = sigm_(p0);
            float og = sigm_(p1);
            float fg = sigm_(p2);
            float cg = tanh_(p3);
            int row = mt * 128 + wm * 64 + i * 16 + qrow * 4 + g;
            size_t off = (size_t)row * H_ + d;
            float c_old = c_src[off];
            float c_new = fg * c_old + ig * cg;
            if (write_c) c_dst[off] = c_new;
            h_dst[off] = og * tanh_(c_new);
        }
    }
}

extern "C" void kernel_launch(void* const* d_in, const int* in_sizes, int n_in,
                              void* d_out, int out_size, void* d_ws, size_t ws_size,
                              hipStream_t stream) {
    const float* node_hidden = (const float*)d_in[0];
    const float* cell        = (const float*)d_in[1];
    const float* w_in        = (const float*)d_in[2];
    const float* w_out       = (const float*)d_in[3];
    const float* u_in        = (const float*)d_in[4];
    const float* u_out       = (const float*)d_in[5];
    const float* bias        = (const float*)d_in[6];
    const float* in_mask     = (const float*)d_in[7];
    const float* out_mask    = (const float*)d_in[8];
    const int*   in_idx      = (const int*)d_in[9];
    const int*   out_idx     = (const int*)d_in[10];
    float* out = (float*)d_out;

    char* p = (char*)d_ws;
    unsigned short* wp_hi = (unsigned short*)p; p += (size_t)NTILES * NCHUNK * 512 * 2;      // 384 KB
    unsigned short* wp_lo = (unsigned short*)p; p += (size_t)NTILES * NCHUNK * 512 * 2;
    unsigned short* A_hi  = (unsigned short*)p; p += (size_t)(M_/16) * NCHUNK * 512 * 2;     // 12 MB
    unsigned short* A_lo  = (unsigned short*)p; p += (size_t)(M_/16) * NCHUNK * 512 * 2;
    float* h_buf = (float*)p;                   p += (size_t)M_ * H_ * 4;                    // 8 MB
    // total ~33 MB; layer-0 c lives in d_out (overwritten by layer-1 h)

    // layer 0 agg + W prep in one dispatch
    agg0_prep_kernel<<<AGG_BLOCKS + PREP_BLOCKS, 256, 0, stream>>>(
        node_hidden, in_idx, in_mask, out_idx, out_mask, A_hi, A_lo,
        w_in, w_out, u_in, u_out, wp_hi, wp_lo);
    gemm_gates<<<GEMM_BLOCKS, 256, 0, stream>>>(
        A_hi, A_lo, wp_hi, wp_lo, bias, cell, out, h_buf, 1);

    // layer 1
    agg_kernel<<<AGG_BLOCKS, 256, 0, stream>>>(h_buf, in_idx, in_mask,
                                               out_idx, out_mask, A_hi, A_lo);
    gemm_gates<<<GEMM_BLOCKS, 256, 0, stream>>>(
        A_hi, A_lo, wp_hi, wp_lo, bias, out, out, out, 0);
}

// Round 2
// 185.311 us; speedup vs baseline: 1.0328x; 1.0328x over previous
//
#include <hip/hip_runtime.h>
#include <math.h>

#define B_ 8
#define N_ 2000
#define H_ 128
#define K_ 32
#define M_ (B_*N_)     // 16000
#define KTOT 384       // [in_agg(128) | out_agg(128) | h(128)]
#define NC 512         // cols j = d*4 + g
#define NTILES 32      // NC/16
#define NCHUNK 12      // KTOT/32
#define AGG_BLOCKS (M_ / 8)           // 2000
#define PREP_BLOCKS (NTILES * NCHUNK) // 384
#define GEMM_BLOCKS 1024              // 8 XCDs x <=128 tile-slots (128x64 tiles)
#define CH_SH (24 * 512)              // shorts per chunk buffer (24 KB)

typedef __attribute__((ext_vector_type(8))) short s8_t;
typedef __attribute__((ext_vector_type(4))) float f4_t;

__device__ __forceinline__ unsigned short f2bf(float x) {
    union { float f; unsigned u; } v; v.f = x;
    unsigned r = v.u + 0x7fff + ((v.u >> 16) & 1);   // RN-even
    return (unsigned short)(r >> 16);
}
__device__ __forceinline__ float bf2f(unsigned short b) {
    union { unsigned u; float f; } v; v.u = (unsigned)b << 16; return v.f;
}
__device__ __forceinline__ float sigm_(float x) { return 1.f / (1.f + __expf(-x)); }
__device__ __forceinline__ float tanh_(float x) { return 2.f / (1.f + __expf(-2.f * x)) - 1.f; }

__device__ __forceinline__ float pickv(f4_t A, int m) {
    float ab = (m & 1) ? A.y : A.x;
    float cd = (m & 1) ? A.w : A.z;
    return (m & 2) ? cd : ab;
}
__device__ __forceinline__ float pick4(float u0, float u1, float u2, float u3, int m) {
    float ab = (m & 1) ? u1 : u0;
    float cd = (m & 1) ? u3 : u2;
    return (m & 2) ? cd : ab;
}

__device__ __forceinline__ void split4(const float* f, ushort4& hi, ushort4& lo) {
    unsigned short h0 = f2bf(f[0]), h1 = f2bf(f[1]), h2 = f2bf(f[2]), h3 = f2bf(f[3]);
    hi = make_ushort4(h0, h1, h2, h3);
    lo = make_ushort4(f2bf(f[0] - bf2f(h0)), f2bf(f[1] - bf2f(h1)),
                      f2bf(f[2] - bf2f(h2)), f2bf(f[3] - bf2f(h3)));
}

// async global->LDS, 16 B per lane; LDS dest = wave-uniform base + lane*16
__device__ __forceinline__ void gload_lds(const unsigned short* g, short* l) {
    __builtin_amdgcn_global_load_lds(
        (const __attribute__((address_space(1))) unsigned*)g,
        (__attribute__((address_space(3))) unsigned*)l, 16, 0, 0);
}

// W prep: element t (0..511) of prep-block pb = (ntile*NCHUNK + chunk).
__device__ __forceinline__ void prep_elem(int pb, int t,
                                          const float* __restrict__ w_in,
                                          const float* __restrict__ w_out,
                                          const float* __restrict__ u_in,
                                          const float* __restrict__ u_out,
                                          unsigned short* __restrict__ wp_hi,
                                          unsigned short* __restrict__ wp_lo) {
    int ntile = pb / NCHUNK, chunk = pb % NCHUNK;
    int lane = t >> 3, e = t & 7;
    int col = ntile * 16 + (lane & 15);
    int k = chunk * 32 + (lane >> 4) * 8 + e;
    int d = col >> 2, g = col & 3;
    float v;
    if (k < 128) {
        v = w_in[(g * 128 + k) * 128 + d];
    } else if (k < 256) {
        v = w_out[(g * 128 + (k - 128)) * 128 + d];
    } else {
        int kk = k - 256;
        v = u_in[(g * 128 + kk) * 128 + d] + u_out[(g * 128 + kk) * 128 + d];
    }
    unsigned short hs = f2bf(v);
    wp_hi[(size_t)pb * 512 + t] = hs;
    wp_lo[(size_t)pb * 512 + t] = f2bf(v - bf2f(hs));
}

// Gather + masked aggregate + u-term pack for agg-unit a (rows 8a..8a+7);
// output split-bf16 in MFMA A-fragment layout (verified R4-R11).
__device__ __forceinline__ void agg_body(int a, int tid,
                                         const float* __restrict__ h,
                                         const int* __restrict__ in_idx,
                                         const float* __restrict__ in_mask,
                                         const int* __restrict__ out_idx,
                                         const float* __restrict__ out_mask,
                                         unsigned short* __restrict__ A_hi,
                                         unsigned short* __restrict__ A_lo,
                                         int (*s_idx)[64], float (*s_msk)[64]) {
    int r = tid >> 5;            // 0..7 row within unit
    int p = tid & 31;            // dim group: dims p*4 .. p*4+3
    int row = a * 8 + r;
    int b = row / N_;
    const float* hb = h + (size_t)b * N_ * H_;

    for (int e = tid; e < 512; e += 256) {
        int r2 = e >> 6, q = e & 63;
        int ridx = a * 8 + r2;
        if (q < 32) {
            s_idx[r2][q] = in_idx[ridx * K_ + q];
            s_msk[r2][q] = in_mask[ridx * K_ + q];
        } else {
            s_idx[r2][q] = out_idx[ridx * K_ + (q - 32)];
            s_msk[r2][q] = out_mask[ridx * K_ + (q - 32)];
        }
    }
    __syncthreads();

    int d0 = p * 4;
    float ai[4] = {0.f, 0.f, 0.f, 0.f};
    float ao[4] = {0.f, 0.f, 0.f, 0.f};
    #pragma unroll 16
    for (int k = 0; k < K_; ++k) {
        int   i1 = s_idx[r][k];
        float m1 = s_msk[r][k];
        int   i2 = s_idx[r][32 + k];
        float m2 = s_msk[r][32 + k];
        float4 v1 = *(const float4*)(hb + (size_t)i1 * H_ + d0);
        float4 v2 = *(const float4*)(hb + (size_t)i2 * H_ + d0);
        ai[0] += m1 * v1.x; ai[1] += m1 * v1.y; ai[2] += m1 * v1.z; ai[3] += m1 * v1.w;
        ao[0] += m2 * v2.x; ao[1] += m2 * v2.y; ao[2] += m2 * v2.z; ao[3] += m2 * v2.w;
    }
    float4 hv4 = *(const float4*)(h + (size_t)row * H_ + d0);
    float hh[4] = {hv4.x, hv4.y, hv4.z, hv4.w};

    int mtile = row >> 4;
    int kg = (p >> 1) & 3;
    int e0 = (p & 1) * 4;
    int lane = (row & 15) + 16 * kg;
    size_t bi = ((size_t)(mtile * NCHUNK +     (p >> 3)) * 64 + lane) * 8 + e0;
    size_t bo = ((size_t)(mtile * NCHUNK + 4 + (p >> 3)) * 64 + lane) * 8 + e0;
    size_t bh = ((size_t)(mtile * NCHUNK + 8 + (p >> 3)) * 64 + lane) * 8 + e0;

    ushort4 hi, lo;
    split4(ai, hi, lo); *(ushort4*)(A_hi + bi) = hi; *(ushort4*)(A_lo + bi) = lo;
    split4(ao, hi, lo); *(ushort4*)(A_hi + bo) = hi; *(ushort4*)(A_lo + bo) = lo;
    split4(hh, hi, lo); *(ushort4*)(A_hi + bh) = hi; *(ushort4*)(A_lo + bh) = lo;
}

// Layer-0 combined dispatch: blocks [0,2000) = agg on node_hidden,
// blocks [2000, 2384) = W prep.
__global__ __launch_bounds__(256)
void agg0_prep_kernel(const float* __restrict__ h,
                      const int* __restrict__ in_idx,
                      const float* __restrict__ in_mask,
                      const int* __restrict__ out_idx,
                      const float* __restrict__ out_mask,
                      unsigned short* __restrict__ A_hi,
                      unsigned short* __restrict__ A_lo,
                      const float* __restrict__ w_in,
                      const float* __restrict__ w_out,
                      const float* __restrict__ u_in,
                      const float* __restrict__ u_out,
                      unsigned short* __restrict__ wp_hi,
                      unsigned short* __restrict__ wp_lo) {
    __shared__ int   s_idx[8][64];
    __shared__ float s_msk[8][64];
    int tid = threadIdx.x;
    if (blockIdx.x < AGG_BLOCKS) {
        int bid = (blockIdx.x & 7) * 250 + (blockIdx.x >> 3);  // XCD-affinity swizzle
        agg_body(bid, tid, h, in_idx, in_mask, out_idx, out_mask,
                 A_hi, A_lo, s_idx, s_msk);
    } else {
        int pb = blockIdx.x - AGG_BLOCKS;
        prep_elem(pb, tid,       w_in, w_out, u_in, u_out, wp_hi, wp_lo);
        prep_elem(pb, tid + 256, w_in, w_out, u_in, u_out, wp_hi, wp_lo);
    }
}

// Layer-1 agg (h = h_buf)
__global__ __launch_bounds__(256)
void agg_kernel(const float* __restrict__ h,
                const int* __restrict__ in_idx,
                const float* __restrict__ in_mask,
                const int* __restrict__ out_idx,
                const float* __restrict__ out_mask,
                unsigned short* __restrict__ A_hi,
                unsigned short* __restrict__ A_lo) {
    __shared__ int   s_idx[8][64];
    __shared__ float s_msk[8][64];
    int bid = (blockIdx.x & 7) * 250 + (blockIdx.x >> 3);
    agg_body(bid, threadIdx.x, h, in_idx, in_mask, out_idx, out_mask,
             A_hi, A_lo, s_idx, s_msk);
}

__device__ __forceinline__ void frag_load(const short* sb, int wm, int wn, int lane,
                                          s8_t (&ah)[4], s8_t (&al)[4],
                                          s8_t (&bh)[2], s8_t (&bl)[2]) {
    #pragma unroll
    for (int i = 0; i < 4; ++i) {
        ah[i] = *(const s8_t*)&sb[(wm * 4 + i) * 512 + lane * 8];
        al[i] = *(const s8_t*)&sb[(8 + wm * 4 + i) * 512 + lane * 8];
    }
    #pragma unroll
    for (int j = 0; j < 2; ++j) {
        bh[j] = *(const s8_t*)&sb[(16 + wn * 2 + j) * 512 + lane * 8];
        bl[j] = *(const s8_t*)&sb[(20 + wn * 2 + j) * 512 + lane * 8];
    }
}

__device__ __forceinline__ void mfma_chunk(
        const s8_t (&ah)[4], const s8_t (&al)[4],
        const s8_t (&bh)[2], const s8_t (&bl)[2],
        f4_t (&acc)[4][2]) {
    #pragma unroll
    for (int i = 0; i < 4; ++i)
        #pragma unroll
        for (int j = 0; j < 2; ++j) {
            acc[i][j] = __builtin_amdgcn_mfma_f32_16x16x32_bf16(ah[i], bh[j], acc[i][j], 0, 0, 0);
            acc[i][j] = __builtin_amdgcn_mfma_f32_16x16x32_bf16(ah[i], bl[j], acc[i][j], 0, 0, 0);
            acc[i][j] = __builtin_amdgcn_mfma_f32_16x16x32_bf16(al[i], bh[j], acc[i][j], 0, 0, 0);
        }
}

// gemm v6: 128x64 tile, 2-deep LDS double-buffer with COUNTED vmcnt
// (catalog T3+T4 minimum 2-phase). Per chunk each wave issues exactly 6
// global_load_lds; stage of chunk c+1 is issued BEFORE waiting for chunk c
// (vmcnt(6) = "my previous 6 landed"). Raw s_barrier via asm (memory
// clobber = compiler fence, and hipcc cannot insert a vmcnt(0) drain).
// LDS 48 KB -> 3 blocks/CU; launch_bounds(256,3) matches the VGPR cap.
__global__ __launch_bounds__(256, 3)
void gemm_gates(const unsigned short* __restrict__ A_hi,
                const unsigned short* __restrict__ A_lo,
                const unsigned short* __restrict__ wp_hi,
                const unsigned short* __restrict__ wp_lo,
                const float* __restrict__ bias,
                const float* __restrict__ c_src,
                float* __restrict__ c_dst,
                float* __restrict__ h_dst,
                int write_c) {
    __shared__ short sL[2 * CH_SH];   // 48 KB
    int l = blockIdx.x;
    int x = l & 7;                   // XCD (round-robin dispatch)
    int s_slot = l >> 3;             // 0..127
    int mt_lo  = x ? ((2000 * x + 63) >> 7) : 0;
    int mt_nxt = (2000 * (x + 1) + 63) >> 7;         // x=7 -> 125
    int cnt = (mt_nxt - mt_lo) * 8;                  // <=128
    if (s_slot >= cnt) return;
    int mt = mt_lo + (s_slot >> 3);                  // 0..124 (128-row tile)
    int jt = s_slot & 7;                             // 0..7  (64-col tile)

    int tid  = threadIdx.x;
    int lane = tid & 63;
    int w    = tid >> 6;         // 0..3
    int wm   = w & 1;            // 64-row half
    int wn   = w >> 1;           // 32-col half
    int mtile0 = mt * 8;
    int ntile0 = jt * 4;

    // staging: wave w owns slots {w, w+4, ..., w+20} (6 each)
    const unsigned short* gp[6];
    short* lpA[6];
    short* lpB[6];
    #pragma unroll
    for (int i = 0; i < 6; ++i) {
        int s = i * 4 + w;
        const unsigned short* src;
        if (s < 8)       src = A_hi  + ((size_t)((mtile0 + s)      * NCHUNK) * 64 + lane) * 8;
        else if (s < 16) src = A_lo  + ((size_t)((mtile0 + s - 8)  * NCHUNK) * 64 + lane) * 8;
        else if (s < 20) src = wp_hi + ((size_t)((ntile0 + s - 16) * NCHUNK) * 64 + lane) * 8;
        else             src = wp_lo + ((size_t)((ntile0 + s - 20) * NCHUNK) * 64 + lane) * 8;
        gp[i] = src;
        lpA[i] = &sL[s * 512];            // buffer 0 (wave-uniform base; HW adds lane*16 B)
        lpB[i] = &sL[CH_SH + s * 512];    // buffer 1
    }

    f4_t zero = {0.f, 0.f, 0.f, 0.f};
    f4_t acc[4][2];
    #pragma unroll
    for (int i = 0; i < 4; ++i)
        #pragma unroll
        for (int j = 0; j < 2; ++j) acc[i][j] = zero;

    s8_t ah[4], al[4], bh[2], bl[2];

    // prologue: stage chunk 0 -> buffer A
    #pragma unroll
    for (int i = 0; i < 6; ++i) { gload_lds(gp[i], lpA[i]); gp[i] += 512; }

    #pragma unroll 1
    for (int c = 0; c < NCHUNK; c += 2) {
        // ---- even phase: compute chunk c (buf A), stage c+1 -> buf B ----
        if (c + 1 < NCHUNK) {
            #pragma unroll
            for (int i = 0; i < 6; ++i) { gload_lds(gp[i], lpB[i]); gp[i] += 512; }
            asm volatile("s_waitcnt vmcnt(6)" ::: "memory");
        } else {
            asm volatile("s_waitcnt vmcnt(0)" ::: "memory");
        }
        asm volatile("s_barrier" ::: "memory");
        frag_load(sL, wm, wn, lane, ah, al, bh, bl);
        asm volatile("s_waitcnt lgkmcnt(0)" ::: "memory");
        __builtin_amdgcn_sched_barrier(0);
        asm volatile("s_barrier" ::: "memory");
        mfma_chunk(ah, al, bh, bl, acc);

        // ---- odd phase: compute chunk c+1 (buf B), stage c+2 -> buf A ----
        if (c + 2 < NCHUNK) {
            #pragma unroll
            for (int i = 0; i < 6; ++i) { gload_lds(gp[i], lpA[i]); gp[i] += 512; }
            asm volatile("s_waitcnt vmcnt(6)" ::: "memory");
        } else {
            asm volatile("s_waitcnt vmcnt(0)" ::: "memory");
        }
        asm volatile("s_barrier" ::: "memory");
        frag_load(sL + CH_SH, wm, wn, lane, ah, al, bh, bl);
        asm volatile("s_waitcnt lgkmcnt(0)" ::: "memory");
        __builtin_amdgcn_sched_barrier(0);
        asm volatile("s_barrier" ::: "memory");
        mfma_chunk(ah, al, bh, bl, acc);
    }

    // ---- epilogue: gate exchange + cell/h update (verified R2-R11) ----
    int g    = lane & 3;
    int qrow = lane >> 4;
    int dl   = (lane >> 2) & 3;
    #pragma unroll
    for (int j = 0; j < 2; ++j) {
        int ncol_base = jt * 64 + wn * 32 + j * 16;
        int d = (ncol_base >> 2) + dl;
        float b0 = bias[0 * 128 + d];
        float b1 = bias[1 * 128 + d];
        float b2 = bias[2 * 128 + d];
        float b3 = bias[3 * 128 + d];
        #pragma unroll
        for (int i = 0; i < 4; ++i) {
            f4_t A = acc[i][j];
            float s0 = pickv(A, g);
            float s1 = pickv(A, g ^ 1);
            float s2 = pickv(A, g ^ 2);
            float s3 = pickv(A, g ^ 3);
            float u0 = s0;
            float u1 = __shfl_xor(s1, 1);
            float u2 = __shfl_xor(s2, 2);
            float u3 = __shfl_xor(s3, 3);
            float p0 = pick4(u0, u1, u2, u3, g) + b0;
            float p1 = pick4(u0, u1, u2, u3, g ^ 1) + b1;
            float p2 = pick4(u0, u1, u2, u3, g ^ 2) + b2;
            float p3 = pick4(u0, u1, u2, u3, g ^ 3) + b3;
            float ig = sigm_(p0);
            float og = sigm_(p1);
            float fg = sigm_(p2);
            float cg = tanh_(p3);
            int row = mt * 128 + wm * 64 + i * 16 + qrow * 4 + g;
            size_t off = (size_t)row * H_ + d;
            float c_old = c_src[off];
            float c_new = fg * c_old + ig * cg;
            if (write_c) c_dst[off] = c_new;
            h_dst[off] = og * tanh_(c_new);
        }
    }
}

extern "C" void kernel_launch(void* const* d_in, const int* in_sizes, int n_in,
                              void* d_out, int out_size, void* d_ws, size_t ws_size,
                              hipStream_t stream) {
    const float* node_hidden = (const float*)d_in[0];
    const float* cell        = (const float*)d_in[1];
    const float* w_in        = (const float*)d_in[2];
    const float* w_out       = (const float*)d_in[3];
    const float* u_in        = (const float*)d_in[4];
    const float* u_out       = (const float*)d_in[5];
    const float* bias        = (const float*)d_in[6];
    const float* in_mask     = (const float*)d_in[7];
    const float* out_mask    = (const float*)d_in[8];
    const int*   in_idx      = (const int*)d_in[9];
    const int*   out_idx     = (const int*)d_in[10];
    float* out = (float*)d_out;

    char* p = (char*)d_ws;
    unsigned short* wp_hi = (unsigned short*)p; p += (size_t)NTILES * NCHUNK * 512 * 2;      // 384 KB
    unsigned short* wp_lo = (unsigned short*)p; p += (size_t)NTILES * NCHUNK * 512 * 2;
    unsigned short* A_hi  = (unsigned short*)p; p += (size_t)(M_/16) * NCHUNK * 512 * 2;     // 12 MB
    unsigned short* A_lo  = (unsigned short*)p; p += (size_t)(M_/16) * NCHUNK * 512 * 2;
    float* h_buf = (float*)p;                   p += (size_t)M_ * H_ * 4;                    // 8 MB
    // total ~33 MB; layer-0 c lives in d_out (overwritten by layer-1 h)

    // layer 0 agg + W prep in one dispatch
    agg0_prep_kernel<<<AGG_BLOCKS + PREP_BLOCKS, 256, 0, stream>>>(
        node_hidden, in_idx, in_mask, out_idx, out_mask, A_hi, A_lo,
        w_in, w_out, u_in, u_out, wp_hi, wp_lo);
    gemm_gates<<<GEMM_BLOCKS, 256, 0, stream>>>(
        A_hi, A_lo, wp_hi, wp_lo, bias, cell, out, h_buf, 1);

    // layer 1
    agg_kernel<<<AGG_BLOCKS, 256, 0, stream>>>(h_buf, in_idx, in_mask,
                                               out_idx, out_mask, A_hi, A_lo);
    gemm_gates<<<GEMM_BLOCKS, 256, 0, stream>>>(
        A_hi, A_lo, wp_hi, wp_lo, bias, out, out, out, 0);
}